// Round 1
// baseline (5292.698 us; speedup 1.0000x reference)
//
#include <hip/hip_runtime.h>

// Encoder: L=6 layers of (rel-pos attention + channel-LN + K=3 conv FFN + LN)
// B=4, C=256, T=1024, H=4, KC=64, FC=1024, W=10 (band |j-i|<=10), fp32 throughout.

#define Lz 6
#define Cz 256
#define FCz 1024
#define Hz 4
#define Wz 10
#define Bz 4
#define Tz 1024
#define KCz 64
#define NR 21  // 2W+1

// ---------------------------------------------------------------------------
// Pointwise GEMM: y[b,o,t] = bias[o] + sum_c w[o,c] * x[b,c,t]
// grid (T/64, O/64, B), block (16,16), each thread 4x4.
// ---------------------------------------------------------------------------
__global__ __launch_bounds__(256) void gemm_pw(
    const float* __restrict__ w, const float* __restrict__ bias,
    const float* __restrict__ x, float* __restrict__ y, int O, int Cin) {
  __shared__ float ws[16][68];  // [k][o], stride 68 for 16B-aligned reads
  __shared__ float xs[16][64];  // [k][t]
  const int tx = threadIdx.x, ty = threadIdx.y;
  const int tid = ty * 16 + tx;
  const int t0 = blockIdx.x * 64, o0 = blockIdx.y * 64, b = blockIdx.z;
  const float* xb = x + (size_t)b * Cin * Tz;
  float acc[4][4] = {};
  for (int kk = 0; kk < Cin; kk += 16) {
#pragma unroll
    for (int i = 0; i < 4; i++) {
      int id = i * 256 + tid;
      int kq = id & 15, o = id >> 4;
      ws[kq][o] = w[(size_t)(o0 + o) * Cin + kk + kq];
    }
#pragma unroll
    for (int i = 0; i < 4; i++) {
      int id = i * 256 + tid;
      int t = id & 63, kq = id >> 6;
      xs[kq][t] = xb[(size_t)(kk + kq) * Tz + t0 + t];
    }
    __syncthreads();
#pragma unroll
    for (int kq = 0; kq < 16; kq++) {
      float a[4], bv[4];
#pragma unroll
      for (int i = 0; i < 4; i++) a[i] = ws[kq][ty * 4 + i];
#pragma unroll
      for (int j = 0; j < 4; j++) bv[j] = xs[kq][tx * 4 + j];
#pragma unroll
      for (int i = 0; i < 4; i++)
#pragma unroll
        for (int j = 0; j < 4; j++) acc[i][j] += a[i] * bv[j];
    }
    __syncthreads();
  }
#pragma unroll
  for (int i = 0; i < 4; i++) {
    int o = o0 + ty * 4 + i;
    float bb = bias[o];
    float4 r = make_float4(acc[i][0] + bb, acc[i][1] + bb, acc[i][2] + bb,
                           acc[i][3] + bb);
    *(float4*)&y[((size_t)b * O + o) * Tz + t0 + tx * 4] = r;
  }
}

// ---------------------------------------------------------------------------
// FFN conv (K=3, pad 1/1): y[b,o,t] = act(bias[o] + sum_c sum_k w[o,c,k]*
//   (x[b,c,t+k-1]*mask)), optional relu and output-mask.
// grid (T/64, Cout/64, B), block (16,16), each thread 4x4.
// ---------------------------------------------------------------------------
template <int RELU, int OUTMASK>
__global__ __launch_bounds__(256) void ffn_conv(
    const float* __restrict__ w, const float* __restrict__ bias,
    const float* __restrict__ x, const float* __restrict__ mask,
    float* __restrict__ y, int Cout, int Cin) {
  __shared__ float xs[8][72];   // [c][t0-1 .. t0+64] (66 used)
  __shared__ float wl[64][25];  // [o][c*3+k] (24 used, pad 25)
  const int tx = threadIdx.x, ty = threadIdx.y;
  const int tid = ty * 16 + tx;
  const int t0 = blockIdx.x * 64, o0 = blockIdx.y * 64, b = blockIdx.z;
  const float* xb = x + (size_t)b * Cin * Tz;
  const float* mb = mask + (size_t)b * Tz;
  float acc[4][4] = {};
  for (int cc = 0; cc < Cin; cc += 8) {
    for (int id = tid; id < 8 * 66; id += 256) {
      int u = id % 66, c = id / 66;
      int t = t0 + u - 1;
      float v = 0.f;
      if (t >= 0 && t < Tz) v = xb[(size_t)(cc + c) * Tz + t] * mb[t];
      xs[c][u] = v;
    }
    for (int id = tid; id < 64 * 24; id += 256) {
      int k24 = id % 24, o = id / 24;
      wl[o][k24] = w[(size_t)(o0 + o) * Cin * 3 + cc * 3 + k24];
    }
    __syncthreads();
#pragma unroll
    for (int c = 0; c < 8; c++) {
      float xv[6];
#pragma unroll
      for (int u = 0; u < 6; u++) xv[u] = xs[c][tx * 4 + u];
      float a[4][3];
#pragma unroll
      for (int i = 0; i < 4; i++)
#pragma unroll
        for (int k = 0; k < 3; k++) a[i][k] = wl[ty * 4 + i][c * 3 + k];
#pragma unroll
      for (int i = 0; i < 4; i++)
#pragma unroll
        for (int k = 0; k < 3; k++)
#pragma unroll
          for (int j = 0; j < 4; j++) acc[i][j] += a[i][k] * xv[j + k];
    }
    __syncthreads();
  }
#pragma unroll
  for (int i = 0; i < 4; i++) {
    int o = o0 + ty * 4 + i;
    float bb = bias[o];
    float r[4];
#pragma unroll
    for (int j = 0; j < 4; j++) {
      float v = acc[i][j] + bb;
      if (RELU) v = fmaxf(v, 0.f);
      if (OUTMASK) v *= mb[t0 + tx * 4 + j];
      r[j] = v;
    }
    *(float4*)&y[((size_t)b * Cout + o) * Tz + t0 + tx * 4] =
        make_float4(r[0], r[1], r[2], r[3]);
  }
}

// ---------------------------------------------------------------------------
// Flash-style attention with banded relative-position terms.
// q,k,v,y: [B,C,T]; erk,erv: [21,64] (this layer). grid (T/64, B*H), blk 16x16.
// Thread (ty,tx) owns rows i = ty + 16*ii (ii<4), cols tx*4+jj.
// ---------------------------------------------------------------------------
__global__ __launch_bounds__(256) void attn_kernel(
    const float* __restrict__ q, const float* __restrict__ k,
    const float* __restrict__ v, const float* __restrict__ mask,
    const float* __restrict__ erk, const float* __restrict__ erv,
    float* __restrict__ y) {
  __shared__ float Qs[64][64];  // [d][i] (scaled by 1/8)
  __shared__ float SK[64][65];  // K-tile [d][j] -> P [i][j] -> O [d][i]
  __shared__ float Vs[64][65];  // [d][j]
  __shared__ float band[64][NR];  // raw masked scores on |j-i|<=10 band
  __shared__ float rq[64][NR];    // q . erk  (reused for erv at epilogue)
  __shared__ float mrow[64], lrow[64], arow[64];

  const int tx = threadIdx.x, ty = threadIdx.y;
  const int tid = ty * 16 + tx;
  const int i0 = blockIdx.x * 64;
  const int b = blockIdx.y >> 2, h = blockIdx.y & 3;
  const float* qb = q + ((size_t)b * Cz + h * KCz) * Tz;
  const float* kb = k + ((size_t)b * Cz + h * KCz) * Tz;
  const float* vb = v + ((size_t)b * Cz + h * KCz) * Tz;
  const float* mb = mask + (size_t)b * Tz;

  for (int id = tid; id < 64 * 64; id += 256) {
    int i = id & 63, d = id >> 6;
    Qs[d][i] = qb[(size_t)d * Tz + i0 + i] * 0.125f;
  }
  if (tid < 64) {
    mrow[tid] = -1e30f;
    lrow[tid] = 0.f;
  }
  for (int id = tid; id < 64 * NR; id += 256) band[id / NR][id % NR] = -1e30f;
  __syncthreads();
  // rq[i][r] = sum_d Qs[d][i] * erk[r][d]  (erk reads are L1-resident, 5 KB)
  for (int id = tid; id < 64 * NR; id += 256) {
    int i = id / NR, r = id % NR;
    float s = 0.f;
    for (int d = 0; d < KCz; d++) s += Qs[d][i] * erk[r * KCz + d];
    rq[i][r] = s;
  }

  float qmk[4];
#pragma unroll
  for (int ii = 0; ii < 4; ii++) qmk[ii] = mb[i0 + ty + 16 * ii];

  float acc[4][4] = {};

  for (int j0 = 0; j0 < Tz; j0 += 64) {
    __syncthreads();  // SK/Vs safe to overwrite; also publishes rq on iter 0
    for (int id = tid; id < 64 * 64; id += 256) {
      int j = id & 63, d = id >> 6;
      SK[d][j] = kb[(size_t)d * Tz + j0 + j];
      Vs[d][j] = vb[(size_t)d * Tz + j0 + j];
    }
    float kmk[4];
#pragma unroll
    for (int jj = 0; jj < 4; jj++) kmk[jj] = mb[j0 + tx * 4 + jj];
    __syncthreads();

    // S = (Q/sqrt(kc)) K^T
    float sc[4][4] = {};
#pragma unroll 4
    for (int d = 0; d < 64; d++) {
      float a[4], bv[4];
#pragma unroll
      for (int ii = 0; ii < 4; ii++) a[ii] = Qs[d][ty + 16 * ii];
#pragma unroll
      for (int jj = 0; jj < 4; jj++) bv[jj] = SK[d][tx * 4 + jj];
#pragma unroll
      for (int ii = 0; ii < 4; ii++)
#pragma unroll
        for (int jj = 0; jj < 4; jj++) sc[ii][jj] += a[ii] * bv[jj];
    }
    // rel-K bias (band only), mask, band capture, row-max (shfl over 16 tx)
    float mx[4];
#pragma unroll
    for (int ii = 0; ii < 4; ii++) {
      int i = ty + 16 * ii, ig = i0 + i;
      float m = -1e30f;
#pragma unroll
      for (int jj = 0; jj < 4; jj++) {
        int j = tx * 4 + jj, jg = j0 + j;
        float s = sc[ii][jj];
        int dl = jg - ig;
        if (dl >= -Wz && dl <= Wz) s += rq[i][dl + Wz];
        if (qmk[ii] * kmk[jj] == 0.f) s = -1e4f;
        sc[ii][jj] = s;
        if (dl >= -Wz && dl <= Wz) band[i][dl + Wz] = s;
        m = fmaxf(m, s);
      }
      mx[ii] = m;
    }
#pragma unroll
    for (int off = 1; off < 16; off <<= 1) {
#pragma unroll
      for (int ii = 0; ii < 4; ii++)
        mx[ii] = fmaxf(mx[ii], __shfl_xor(mx[ii], off, 16));
    }
    if (tx == 0) {
#pragma unroll
      for (int ii = 0; ii < 4; ii++) {
        int i = ty + 16 * ii;
        float nm = fmaxf(mrow[i], mx[ii]);
        float al = __expf(mrow[i] - nm);
        mrow[i] = nm;
        arow[i] = al;
        lrow[i] *= al;
      }
    }
    __syncthreads();  // mrow/arow final; K-reads of SK complete

    // P = exp(S - m) -> SK; row-sum via shfl; rescale O accumulator
    float sm[4];
#pragma unroll
    for (int ii = 0; ii < 4; ii++) {
      int i = ty + 16 * ii;
      float m = mrow[i], s = 0.f;
#pragma unroll
      for (int jj = 0; jj < 4; jj++) {
        float p = __expf(sc[ii][jj] - m);
        SK[i][tx * 4 + jj] = p;
        s += p;
      }
      sm[ii] = s;
    }
#pragma unroll
    for (int off = 1; off < 16; off <<= 1) {
#pragma unroll
      for (int ii = 0; ii < 4; ii++) sm[ii] += __shfl_xor(sm[ii], off, 16);
    }
    if (tx == 0) {
#pragma unroll
      for (int ii = 0; ii < 4; ii++) lrow[ty + 16 * ii] += sm[ii];
    }
#pragma unroll
    for (int ii = 0; ii < 4; ii++) {
      float al = arow[ty + 16 * ii];
#pragma unroll
      for (int jj = 0; jj < 4; jj++) acc[ii][jj] *= al;
    }
    __syncthreads();  // P visible

    // O += P V
#pragma unroll 4
    for (int j = 0; j < 64; j++) {
      float p[4], vv[4];
#pragma unroll
      for (int ii = 0; ii < 4; ii++) p[ii] = SK[ty + 16 * ii][j];
#pragma unroll
      for (int jj = 0; jj < 4; jj++) vv[jj] = Vs[tx * 4 + jj][j];
#pragma unroll
      for (int ii = 0; ii < 4; ii++)
#pragma unroll
        for (int jj = 0; jj < 4; jj++) acc[ii][jj] += p[ii] * vv[jj];
    }
  }

  __syncthreads();
  // epilogue: band probs + rel-V, normalize, write coalesced via SK staging
  float* ervs = &rq[0][0];  // rq no longer needed
  for (int id = tid; id < NR * KCz; id += 256) ervs[id] = erv[id];
  for (int id = tid; id < 64 * NR; id += 256) {
    int i = id / NR, r = id % NR;
    band[i][r] = __expf(band[i][r] - mrow[i]);
  }
  __syncthreads();
#pragma unroll
  for (int ii = 0; ii < 4; ii++) {
    int i = ty + 16 * ii;
    float li = 1.f / lrow[i];
    float o[4];
#pragma unroll
    for (int jj = 0; jj < 4; jj++) o[jj] = acc[ii][jj];
    for (int r = 0; r < NR; r++) {
      float pb = band[i][r];
#pragma unroll
      for (int jj = 0; jj < 4; jj++) o[jj] += pb * ervs[r * KCz + tx * 4 + jj];
    }
#pragma unroll
    for (int jj = 0; jj < 4; jj++) acc[ii][jj] = o[jj] * li;
  }
  __syncthreads();  // all PV reads of SK done (covered above), reuse as O[d][i]
#pragma unroll
  for (int ii = 0; ii < 4; ii++)
#pragma unroll
    for (int jj = 0; jj < 4; jj++)
      SK[tx * 4 + jj][ty + 16 * ii] = acc[ii][jj];
  __syncthreads();
  for (int id = tid; id < 64 * 64; id += 256) {
    int i = id & 63, d = id >> 6;
    y[((size_t)b * Cz + h * KCz + d) * Tz + i0 + i] = SK[d][i];
  }
}

// ---------------------------------------------------------------------------
// In-place residual + channel LayerNorm over C: x = LN(x + y)*g + b
// grid (T/64, B), block 256. Two passes over global (L2-resident).
// ---------------------------------------------------------------------------
__global__ __launch_bounds__(256) void add_ln(
    float* __restrict__ x, const float* __restrict__ y,
    const float* __restrict__ g, const float* __restrict__ bb) {
  __shared__ float red[8][64];
  __shared__ float ms[64], rs[64];
  const int tid = threadIdx.x;
  const int t0 = blockIdx.x * 64, b = blockIdx.y;
  const int tl = tid & 63, grp = tid >> 6;  // 4 c-groups
  const size_t base = (size_t)b * Cz * Tz + t0 + tl;
  float s = 0.f, sq = 0.f;
  for (int c = grp; c < Cz; c += 4) {
    float v = x[base + (size_t)c * Tz] + y[base + (size_t)c * Tz];
    s += v;
    sq += v * v;
  }
  red[grp][tl] = s;
  red[4 + grp][tl] = sq;
  __syncthreads();
  if (tid < 64) {
    float su = red[0][tid] + red[1][tid] + red[2][tid] + red[3][tid];
    float sqq = red[4][tid] + red[5][tid] + red[6][tid] + red[7][tid];
    float m = su * (1.f / Cz);
    float var = sqq * (1.f / Cz) - m * m;
    ms[tid] = m;
    rs[tid] = rsqrtf(var + 1e-5f);
  }
  __syncthreads();
  float m = ms[tl], r = rs[tl];
  for (int c = grp; c < Cz; c += 4) {
    float v = x[base + (size_t)c * Tz] + y[base + (size_t)c * Tz];
    x[base + (size_t)c * Tz] = (v - m) * r * g[c] + bb[c];
  }
}

__global__ __launch_bounds__(256) void mask_mul(
    const float* __restrict__ x, const float* __restrict__ mask,
    float* __restrict__ out, int n) {
  int idx = blockIdx.x * 256 + threadIdx.x;
  if (idx < n) {
    int t = idx & (Tz - 1);
    int b = idx / (Cz * Tz);
    out[idx] = x[idx] * mask[b * Tz + t];
  }
}

// ---------------------------------------------------------------------------
extern "C" void kernel_launch(void* const* d_in, const int* in_sizes, int n_in,
                              void* d_out, int out_size, void* d_ws,
                              size_t ws_size, hipStream_t stream) {
  const float* x = (const float*)d_in[0];
  const float* xm = (const float*)d_in[1];
  const float* wq = (const float*)d_in[2];
  const float* bq = (const float*)d_in[3];
  const float* wk = (const float*)d_in[4];
  const float* bk = (const float*)d_in[5];
  const float* wv = (const float*)d_in[6];
  const float* bv = (const float*)d_in[7];
  const float* wo = (const float*)d_in[8];
  const float* bo = (const float*)d_in[9];
  const float* erk = (const float*)d_in[10];
  const float* erv = (const float*)d_in[11];
  const float* g1 = (const float*)d_in[12];
  const float* b1 = (const float*)d_in[13];
  const float* fw1 = (const float*)d_in[14];
  const float* fb1 = (const float*)d_in[15];
  const float* fw2 = (const float*)d_in[16];
  const float* fb2 = (const float*)d_in[17];
  const float* g2 = (const float*)d_in[18];
  const float* b2 = (const float*)d_in[19];

  const size_t NBC = (size_t)Bz * Cz * Tz;  // 1,048,576 floats
  float* ws = (float*)d_ws;
  float* xb = ws;               // current activation
  float* yb = ws + NBC;         // residual branch
  float* qb = ws + 2 * NBC;
  float* kb2 = ws + 3 * NBC;
  float* vb2 = ws + 4 * NBC;
  float* ao = ws + 5 * NBC;
  float* hb = qb;  // FFN hidden [B,FC,T] reuses q/k/v/ao (4*NBC floats)

  dim3 blk(16, 16);
  const int ntot = (int)NBC;
  mask_mul<<<dim3((ntot + 255) / 256), dim3(256), 0, stream>>>(x, xm, xb, ntot);
  for (int l = 0; l < Lz; l++) {
    gemm_pw<<<dim3(16, 4, 4), blk, 0, stream>>>(wq + (size_t)l * Cz * Cz,
                                                bq + l * Cz, xb, qb, Cz, Cz);
    gemm_pw<<<dim3(16, 4, 4), blk, 0, stream>>>(wk + (size_t)l * Cz * Cz,
                                                bk + l * Cz, xb, kb2, Cz, Cz);
    gemm_pw<<<dim3(16, 4, 4), blk, 0, stream>>>(wv + (size_t)l * Cz * Cz,
                                                bv + l * Cz, xb, vb2, Cz, Cz);
    attn_kernel<<<dim3(16, 16), blk, 0, stream>>>(
        qb, kb2, vb2, xm, erk + l * NR * KCz, erv + l * NR * KCz, ao);
    gemm_pw<<<dim3(16, 4, 4), blk, 0, stream>>>(wo + (size_t)l * Cz * Cz,
                                                bo + l * Cz, ao, yb, Cz, Cz);
    add_ln<<<dim3(16, 4), dim3(256), 0, stream>>>(xb, yb, g1 + l * Cz,
                                                  b1 + l * Cz);
    ffn_conv<1, 0><<<dim3(16, 16, 4), blk, 0, stream>>>(
        fw1 + (size_t)l * FCz * Cz * 3, fb1 + l * FCz, xb, xm, hb, FCz, Cz);
    ffn_conv<0, 1><<<dim3(16, 4, 4), blk, 0, stream>>>(
        fw2 + (size_t)l * Cz * FCz * 3, fb2 + l * Cz, hb, xm, yb, Cz, FCz);
    add_ln<<<dim3(16, 4), dim3(256), 0, stream>>>(xb, yb, g2 + l * Cz,
                                                  b2 + l * Cz);
  }
  mask_mul<<<dim3((ntot + 255) / 256), dim3(256), 0, stream>>>(
      xb, xm, (float*)d_out, ntot);
}